// Round 23
// baseline (93.826 us; speedup 1.0000x reference)
//
#include <hip/hip_runtime.h>

#define B_ 32
#define T_ 12
#define F_ 4
#define L_ 1024
#define H_ 64
#define NROWS 1920   // 1536 x rows + 6*64 bias rows
#define NCH 256      // one block per 4-link chunk
#define CONE 8       // 4 own links + MARG margin each side
#define MARG 2

#define LOG2E  1.4426950408889634f
#define LOG2E2 2.8853900817779268f

typedef _Float16 f16x8 __attribute__((ext_vector_type(8)));
typedef float f32x4 __attribute__((ext_vector_type(4)));
typedef unsigned long long u64;

#define MFMA __builtin_amdgcn_mfma_f32_16x16x32_f16

#if __has_builtin(__builtin_amdgcn_exp2f)
#define EXP2F(x) __builtin_amdgcn_exp2f(x)
#else
#define EXP2F(x) __expf((x) * 0.69314718056f)
#endif

// XCD-chunked swizzle: neighboring cones overlap -> shared Wpk lines in L2
__device__ __forceinline__ int chunk_of_block(int bid) {
    return ((bid & 7) << 5) + (bid >> 3);
}
__device__ __forceinline__ int clampi(int v, int lo, int hi) {
    return v < lo ? lo : (v > hi ? hi : v);
}
// LDS h: [parity][slot 0..7][b][k] fp16, XOR-swizzled rows
__device__ __forceinline__ int h_byte(int p, int slot, int b, int k) {
    int byte = ((((p * CONE + slot) * 32 + b) * 64) + k) * 2;
    return byte ^ ((b & 7) << 4);
}

// ---------------------------------------------------------------------------
// Merged prep: blocks 0..479 transpose x+biases into params[l][NROWS];
// blocks 480..1503 pack per-link fp16 MFMA fragments into Wpk (one link per
// block), with exp2 pre-scaling folded into the weights:
//   r,z gate paths x LOG2E ; n gate paths (nh, nx, biases) x 2*LOG2E.
// Wpk[l][f][lane], f = nt*9+s; s: 0,1 r-hidden ks; 2 r-x; 3,4 z-hidden;
// 5 z-x; 6,7 nh-hidden; 8 nx-x. x-frags carry gate bias in K row 4.
// ---------------------------------------------------------------------------
__global__ __launch_bounds__(256) void prep_all(
    const float* __restrict__ x,
    const float* __restrict__ b_rh, const float* __restrict__ b_ri,
    const float* __restrict__ b_uh, const float* __restrict__ b_ui,
    const float* __restrict__ b_nh, const float* __restrict__ b_ni,
    const float* __restrict__ w_rh, const float* __restrict__ w_uh,
    const float* __restrict__ w_nh,
    const float* __restrict__ w_ri, const float* __restrict__ w_ui,
    const float* __restrict__ w_ni,
    float* __restrict__ params, _Float16* __restrict__ Wpk)
{
    __shared__ float sh[3][64][65];   // 49.9 KB, shared by both roles
    const int tid = threadIdx.x;

    if (blockIdx.x < 480) {
        // ---- transpose role
        const int rt = blockIdx.x >> 4;    // 30 row tiles
        const int lt = blockIdx.x & 15;    // 16 link tiles
        float (*lds)[65] = sh[0];
        #pragma unroll
        for (int i = 0; i < 16; ++i) {
            const int e  = i * 256 + tid;
            const int rl = e >> 6, ll = e & 63;
            const int r  = rt * 64 + rl, l = lt * 64 + ll;
            float v;
            if (r < 1536) {
                v = x[(size_t)r * L_ + l];
            } else {
                const int rb = r - 1536;
                const int g  = rb >> 6;
                const float* bp = (g == 0) ? b_rh : (g == 1) ? b_ri : (g == 2) ? b_uh
                                : (g == 3) ? b_ui : (g == 4) ? b_nh : b_ni;
                v = bp[(size_t)(rb & 63) * L_ + l];
            }
            lds[rl][ll] = v;
        }
        __syncthreads();
        #pragma unroll
        for (int i = 0; i < 16; ++i) {
            const int e  = i * 256 + tid;
            const int ll = e >> 6, rl = e & 63;
            params[(size_t)(lt * 64 + ll) * NROWS + rt * 64 + rl] = lds[rl][ll];
        }
        return;
    }

    // ---- weight-pack role (one link per block)
    const int l  = blockIdx.x - 480;
    const int fq = tid >> 6, m = tid & 63;
    const int n  = m & 15, kq = m >> 4;

    const float* whs[3] = { w_rh, w_uh, w_nh };
    #pragma unroll
    for (int g = 0; g < 3; ++g) {
        const float4* src = (const float4*)(whs[g] + (size_t)l * 4096);
        #pragma unroll
        for (int i = 0; i < 4; ++i) {
            const int e4 = i * 256 + tid;          // float4 idx 0..1023
            const float4 v = src[e4];
            const int row = e4 >> 4, col = (e4 & 15) * 4;
            sh[g][row][col]     = v.x;
            sh[g][row][col + 1] = v.y;
            sh[g][row][col + 2] = v.z;
            sh[g][row][col + 3] = v.w;
        }
    }
    __syncthreads();

    #pragma unroll
    for (int i = 0; i < 9; ++i) {
        const int f  = i * 4 + fq;
        const int nt = f / 9, s = f % 9;
        const int grp = s / 3, sub = s % 3;
        const int kout = nt * 16 + n;
        const float scale = (grp == 2) ? LOG2E2 : LOG2E;
        f16x8 v;
        if (sub < 2) {
            #pragma unroll
            for (int j = 0; j < 8; ++j)
                v[j] = (_Float16)(sh[grp][sub * 32 + kq * 8 + j][kout] * scale);
        } else {
            const float* wx = (grp == 0) ? w_ri : (grp == 1) ? w_ui : w_ni;
            float bias;
            if (grp == 0)      bias = b_rh[(size_t)kout * L_ + l] + b_ri[(size_t)kout * L_ + l];
            else if (grp == 1) bias = b_uh[(size_t)kout * L_ + l] + b_ui[(size_t)kout * L_ + l];
            else               bias = b_ni[(size_t)kout * L_ + l];
            #pragma unroll
            for (int j = 0; j < 8; ++j) {
                const int k = kq * 8 + j;
                v[j] = (k < 4) ? (_Float16)(wx[(size_t)l * 256 + k * 64 + kout] * scale)
                     : (k == 4) ? (_Float16)(bias * scale)
                                : (_Float16)0.0f;
            }
        }
        *(f16x8*)(Wpk + (((size_t)l * 36 + f) * 64 + m) * 8) = v;
    }
}

// ---------------------------------------------------------------------------
// Zero-sync truncated-cone GRU, swapped MFMA operands, task-merged, and
// 2 BLOCKS/CU: x is read per-step from L2-resident params (no xls stage),
// cutting LDS to 64.5 KB so two chunks' blocks co-reside per CU
// (16 waves/CU = 4 waves/SIMD latency hiding; adjacent chunks share Wpk L2
// lines via the XCD swizzle). Wave w owns cone slot w for all 64 kout.
// Gate pre-activations arrive pre-scaled (log2e / 2*log2e) -> native exp2.
// ---------------------------------------------------------------------------
__global__ __launch_bounds__(512, 1) void gru_cone(
    const _Float16* __restrict__ Wpk,
    const float* __restrict__ att,  const float* __restrict__ params,
    const float* __restrict__ w_fc, const float* __restrict__ b_fc,
    float* __restrict__ out)
{
    const int c    = chunk_of_block(blockIdx.x);
    const int tid  = threadIdx.x;
    const int w    = tid >> 6, lane = tid & 63;
    const int n    = lane & 15, kq = lane >> 4;
    const int cl   = w;               // cone slot 0..7 (this wave's link)
    const int base = 4 * c - MARG;

    __shared__ __align__(16) _Float16 hbuf[2 * CONE * 32 * 64];  // 64 KB
    __shared__ float psum[4][B_];                                // 0.5 KB

    // ---- zero both h parities (8192 u64)
    #pragma unroll
    for (int i = 0; i < 16; ++i)
        ((u64*)hbuf)[i * 512 + tid] = 0ull;

    // ---- this wave's task constants (one link, all 64 kout)
    const int  gl   = base + cl;
    const bool tval = (gl >= 0 && gl < L_);
    const int  glc  = clampi(gl, 0, L_ - 1);
    const _Float16 ach = tval ? (_Float16)att[(size_t)glc * L_ + glc] : (_Float16)0.0f;
    const _Float16 alh = (tval && cl > 0 && gl > 0)
                           ? (_Float16)att[(size_t)glc * L_ + glc - 1] : (_Float16)0.0f;
    const _Float16 arh = (tval && cl < CONE - 1 && gl < L_ - 1)
                           ? (_Float16)att[(size_t)glc * L_ + glc + 1] : (_Float16)0.0f;
    float bnh[4][4];   // per-q, per-r nh bias, pre-scaled by 2*log2e
    f16x8 xw[4][3];    // hoisted x-frags [q][gate] (bias row folded)
    {
        const float* pb = params + (size_t)glc * NROWS + 1536;
        #pragma unroll
        for (int q = 0; q < 4; ++q) {
            #pragma unroll
            for (int r = 0; r < 4; ++r)
                bnh[q][r] = pb[256 + q * 16 + kq * 4 + r] * LOG2E2;
            #pragma unroll
            for (int g = 0; g < 3; ++g)
                xw[q][g] = *(const f16x8*)(Wpk +
                    (((size_t)glc * 36 + q * 9 + 2 + 3 * g) * 64 + lane) * 8);
        }
    }
    const float* xrow = params + (size_t)glc * NROWS;   // this link's x rows
    __syncthreads();

    // ---- time loop: fully block-local
    #pragma unroll 1
    for (int t = 0; t < T_; ++t) {
        const int rp = t & 1, wpb = rp ^ 1;
        const int need = T_ - 1 - t;                  // forward-cone radius
        const char* hbr = (const char*)hbuf;
        char*       hbw = (char*)hbuf;

        if (tval && cl >= 2 - need && cl <= 5 + need) {
            const bool hid = (t > 0);

            // B-operand fragments (hatt) from LDS, built once for all 4 q
            f16x8 af[2][2];
            if (hid) {
                #pragma unroll
                for (int mt = 0; mt < 2; ++mt)
                    #pragma unroll
                    for (int ks = 0; ks < 2; ++ks) {
                        const int b = mt * 16 + n, k0 = ks * 32 + kq * 8;
                        const int sl = (cl > 0) ? cl - 1 : 0;
                        const int sr = (cl < CONE - 1) ? cl + 1 : CONE - 1;
                        const f16x8 hs = *(const f16x8*)(hbr + h_byte(rp, cl, b, k0));
                        const f16x8 hl = *(const f16x8*)(hbr + h_byte(rp, sl, b, k0));
                        const f16x8 hr = *(const f16x8*)(hbr + h_byte(rp, sr, b, k0));
                        af[mt][ks] = ach * hs + alh * hl + arh * hr;
                    }
            }
            // x B-fragment: float4 from L2-resident params (16B aligned)
            f16x8 ax[2] = {};
            if (kq == 0) {
                #pragma unroll
                for (int mt = 0; mt < 2; ++mt) {
                    const float4 xb = *(const float4*)(xrow + (mt * 16 + n) * 48 + t * 4);
                    ax[mt][0] = (_Float16)xb.x; ax[mt][1] = (_Float16)xb.y;
                    ax[mt][2] = (_Float16)xb.z; ax[mt][3] = (_Float16)xb.w;
                    ax[mt][4] = (_Float16)1.0f;
                }
            }

            float sfc[2] = {0.0f, 0.0f};
            #pragma unroll
            for (int q = 0; q < 4; ++q) {
                const int kb = q * 16 + kq * 4;           // this thread's kout run
                const _Float16* wb = Wpk + (((size_t)gl * 36 + q * 9) * 64) * 8;
                f32x4 ar[2] = {}, az[2] = {}, anh_[2] = {}, anx_[2] = {};
                if (hid) {
                    const f16x8 b0 = *(const f16x8*)(wb + (0 * 64 + lane) * 8);
                    const f16x8 b1 = *(const f16x8*)(wb + (1 * 64 + lane) * 8);
                    const f16x8 b3 = *(const f16x8*)(wb + (3 * 64 + lane) * 8);
                    const f16x8 b4 = *(const f16x8*)(wb + (4 * 64 + lane) * 8);
                    const f16x8 b6 = *(const f16x8*)(wb + (6 * 64 + lane) * 8);
                    const f16x8 b7 = *(const f16x8*)(wb + (7 * 64 + lane) * 8);
                    #pragma unroll
                    for (int mt = 0; mt < 2; ++mt) {
                        ar[mt]   = MFMA(b0, af[mt][0], ar[mt],   0, 0, 0);
                        ar[mt]   = MFMA(b1, af[mt][1], ar[mt],   0, 0, 0);
                        az[mt]   = MFMA(b3, af[mt][0], az[mt],   0, 0, 0);
                        az[mt]   = MFMA(b4, af[mt][1], az[mt],   0, 0, 0);
                        anh_[mt] = MFMA(b6, af[mt][0], anh_[mt], 0, 0, 0);
                        anh_[mt] = MFMA(b7, af[mt][1], anh_[mt], 0, 0, 0);
                    }
                }
                #pragma unroll
                for (int mt = 0; mt < 2; ++mt) {
                    ar[mt]   = MFMA(xw[q][0], ax[mt], ar[mt],   0, 0, 0);
                    az[mt]   = MFMA(xw[q][1], ax[mt], az[mt],   0, 0, 0);
                    anx_[mt] = MFMA(xw[q][2], ax[mt], anx_[mt], 0, 0, 0);
                }
                float4 wfc4;
                if (t == T_ - 1)
                    wfc4 = *(const float4*)&w_fc[(size_t)gl * H_ + kb];
                #pragma unroll
                for (int mt = 0; mt < 2; ++mt) {
                    const int b = mt * 16 + n;
                    // z-blend previous state: one contiguous b64 (4 kout)
                    union { u64 u; _Float16 h[4]; } hp;
                    hp.u = hid ? *(const u64*)(hbr + h_byte(rp, cl, b, kb)) : 0ull;
                    union { u64 u; _Float16 h[4]; } hvp;
                    #pragma unroll
                    for (int r = 0; r < 4; ++r) {
                        // pre-scaled pre-activations -> native 2^x throughout
                        const float rg = __builtin_amdgcn_rcpf(1.0f + EXP2F(-ar[mt][r]));
                        const float zg = __builtin_amdgcn_rcpf(1.0f + EXP2F(-az[mt][r]));
                        float npre = anx_[mt][r] + rg * (anh_[mt][r] + bnh[q][r]);
                        npre = fminf(fmaxf(npre, -43.0f), 43.0f);
                        const float e2 = EXP2F(npre);
                        const float nn = (e2 - 1.0f) * __builtin_amdgcn_rcpf(e2 + 1.0f);
                        const float hv = (1.0f - zg) * nn + zg * (float)hp.h[r];
                        hvp.h[r] = (_Float16)hv;
                        if (t == T_ - 1) sfc[mt] += hv * (&wfc4.x)[r];
                    }
                    if (t < T_ - 1)
                        *(u64*)(hbw + h_byte(wpb, cl, b, kb)) = hvp.u;
                }
            }
            if (t == T_ - 1) {   // only own slots (cl 2..5) reach here
                #pragma unroll
                for (int mt = 0; mt < 2; ++mt) {
                    float s = sfc[mt];
                    s += __shfl_xor(s, 16, 64);   // reduce over kq
                    s += __shfl_xor(s, 32, 64);
                    if (kq == 0) psum[cl - 2][mt * 16 + n] = s;
                }
            }
        }
        __syncthreads();   // h[wpb] complete (and, at t=11, psum complete)
    }

    // ---- FC combine epilogue
    if (tid < 128) {
        const int o = tid >> 5, b = tid & 31;
        const int gl2 = 4 * c + o;
        out[(size_t)b * L_ + gl2] = psum[o][b] + b_fc[gl2];
    }
}

extern "C" void kernel_launch(void* const* d_in, const int* in_sizes, int n_in,
                              void* d_out, int out_size, void* d_ws, size_t ws_size,
                              hipStream_t stream) {
    const float* x    = (const float*)d_in[0];
    const float* att  = (const float*)d_in[1];
    const float* w_rh = (const float*)d_in[2];
    const float* b_rh = (const float*)d_in[3];
    const float* w_ri = (const float*)d_in[4];
    const float* b_ri = (const float*)d_in[5];
    const float* w_uh = (const float*)d_in[6];
    const float* b_uh = (const float*)d_in[7];
    const float* w_ui = (const float*)d_in[8];
    const float* b_ui = (const float*)d_in[9];
    const float* w_nh = (const float*)d_in[10];
    const float* b_nh = (const float*)d_in[11];
    const float* w_ni = (const float*)d_in[12];
    const float* b_ni = (const float*)d_in[13];
    const float* w_fc = (const float*)d_in[14];
    const float* b_fc = (const float*)d_in[15];
    float* out = (float*)d_out;

    char* ws = (char*)d_ws;
    float*    params = (float*)ws;                    // 7.9 MB
    _Float16* Wpk    = (_Float16*)(ws + (8u << 20));  // 37.7 MB packed weights

    prep_all<<<1504, 256, 0, stream>>>(x, b_rh, b_ri, b_uh, b_ui, b_nh, b_ni,
                                       w_rh, w_uh, w_nh, w_ri, w_ui, w_ni,
                                       params, Wpk);
    gru_cone<<<NCH, 512, 0, stream>>>(Wpk, att, params, w_fc, b_fc, out);
}

// Round 24
// 90.006 us; speedup vs baseline: 1.0424x; 1.0424x over previous
//
#include <hip/hip_runtime.h>

#define B_ 32
#define T_ 12
#define F_ 4
#define L_ 1024
#define H_ 64
#define NROWS 1920   // 1536 x rows + 6*64 bias rows
#define NCH 256      // one block per 4-link chunk
#define CONE 8       // 4 own links + MARG margin each side
#define MARG 2

#define LOG2E  1.4426950408889634f
#define LOG2E2 2.8853900817779268f

typedef _Float16 f16x8 __attribute__((ext_vector_type(8)));
typedef float f32x4 __attribute__((ext_vector_type(4)));
typedef unsigned long long u64;

#define MFMA __builtin_amdgcn_mfma_f32_16x16x32_f16

#if __has_builtin(__builtin_amdgcn_exp2f)
#define EXP2F(x) __builtin_amdgcn_exp2f(x)
#else
#define EXP2F(x) __expf((x) * 0.69314718056f)
#endif

// XCD-chunked swizzle: neighboring cones overlap -> shared Wpk lines in L2
__device__ __forceinline__ int chunk_of_block(int bid) {
    return ((bid & 7) << 5) + (bid >> 3);
}
__device__ __forceinline__ int clampi(int v, int lo, int hi) {
    return v < lo ? lo : (v > hi ? hi : v);
}
// LDS h: [parity][slot 0..7][b][k] fp16, XOR-swizzled rows
__device__ __forceinline__ int h_byte(int p, int slot, int b, int k) {
    int byte = ((((p * CONE + slot) * 32 + b) * 64) + k) * 2;
    return byte ^ ((b & 7) << 4);
}

// ---------------------------------------------------------------------------
// Merged prep: blocks 0..479 transpose x+biases into params[l][NROWS];
// blocks 480..1503 pack per-link fp16 MFMA fragments into Wpk (one link per
// block), with exp2 pre-scaling folded into the weights:
//   r,z gate paths x LOG2E ; n gate paths (nh, nx, biases) x 2*LOG2E.
// Wpk[l][f][lane], f = nt*9+s; s: 0,1 r-hidden ks; 2 r-x; 3,4 z-hidden;
// 5 z-x; 6,7 nh-hidden; 8 nx-x. x-frags carry gate bias in K row 4.
// ---------------------------------------------------------------------------
__global__ __launch_bounds__(256) void prep_all(
    const float* __restrict__ x,
    const float* __restrict__ b_rh, const float* __restrict__ b_ri,
    const float* __restrict__ b_uh, const float* __restrict__ b_ui,
    const float* __restrict__ b_nh, const float* __restrict__ b_ni,
    const float* __restrict__ w_rh, const float* __restrict__ w_uh,
    const float* __restrict__ w_nh,
    const float* __restrict__ w_ri, const float* __restrict__ w_ui,
    const float* __restrict__ w_ni,
    float* __restrict__ params, _Float16* __restrict__ Wpk)
{
    __shared__ float sh[3][64][65];   // 49.9 KB, shared by both roles
    const int tid = threadIdx.x;

    if (blockIdx.x < 480) {
        // ---- transpose role
        const int rt = blockIdx.x >> 4;    // 30 row tiles
        const int lt = blockIdx.x & 15;    // 16 link tiles
        float (*lds)[65] = sh[0];
        #pragma unroll
        for (int i = 0; i < 16; ++i) {
            const int e  = i * 256 + tid;
            const int rl = e >> 6, ll = e & 63;
            const int r  = rt * 64 + rl, l = lt * 64 + ll;
            float v;
            if (r < 1536) {
                v = x[(size_t)r * L_ + l];
            } else {
                const int rb = r - 1536;
                const int g  = rb >> 6;
                const float* bp = (g == 0) ? b_rh : (g == 1) ? b_ri : (g == 2) ? b_uh
                                : (g == 3) ? b_ui : (g == 4) ? b_nh : b_ni;
                v = bp[(size_t)(rb & 63) * L_ + l];
            }
            lds[rl][ll] = v;
        }
        __syncthreads();
        #pragma unroll
        for (int i = 0; i < 16; ++i) {
            const int e  = i * 256 + tid;
            const int ll = e >> 6, rl = e & 63;
            params[(size_t)(lt * 64 + ll) * NROWS + rt * 64 + rl] = lds[rl][ll];
        }
        return;
    }

    // ---- weight-pack role (one link per block)
    const int l  = blockIdx.x - 480;
    const int fq = tid >> 6, m = tid & 63;
    const int n  = m & 15, kq = m >> 4;

    const float* whs[3] = { w_rh, w_uh, w_nh };
    #pragma unroll
    for (int g = 0; g < 3; ++g) {
        const float4* src = (const float4*)(whs[g] + (size_t)l * 4096);
        #pragma unroll
        for (int i = 0; i < 4; ++i) {
            const int e4 = i * 256 + tid;          // float4 idx 0..1023
            const float4 v = src[e4];
            const int row = e4 >> 4, col = (e4 & 15) * 4;
            sh[g][row][col]     = v.x;
            sh[g][row][col + 1] = v.y;
            sh[g][row][col + 2] = v.z;
            sh[g][row][col + 3] = v.w;
        }
    }
    __syncthreads();

    #pragma unroll
    for (int i = 0; i < 9; ++i) {
        const int f  = i * 4 + fq;
        const int nt = f / 9, s = f % 9;
        const int grp = s / 3, sub = s % 3;
        const int kout = nt * 16 + n;
        const float scale = (grp == 2) ? LOG2E2 : LOG2E;
        f16x8 v;
        if (sub < 2) {
            #pragma unroll
            for (int j = 0; j < 8; ++j)
                v[j] = (_Float16)(sh[grp][sub * 32 + kq * 8 + j][kout] * scale);
        } else {
            const float* wx = (grp == 0) ? w_ri : (grp == 1) ? w_ui : w_ni;
            float bias;
            if (grp == 0)      bias = b_rh[(size_t)kout * L_ + l] + b_ri[(size_t)kout * L_ + l];
            else if (grp == 1) bias = b_uh[(size_t)kout * L_ + l] + b_ui[(size_t)kout * L_ + l];
            else               bias = b_ni[(size_t)kout * L_ + l];
            #pragma unroll
            for (int j = 0; j < 8; ++j) {
                const int k = kq * 8 + j;
                v[j] = (k < 4) ? (_Float16)(wx[(size_t)l * 256 + k * 64 + kout] * scale)
                     : (k == 4) ? (_Float16)(bias * scale)
                                : (_Float16)0.0f;
            }
        }
        *(f16x8*)(Wpk + (((size_t)l * 36 + f) * 64 + m) * 8) = v;
    }
}

// ---------------------------------------------------------------------------
// Zero-sync truncated-cone GRU, swapped MFMA operands, TASK-MERGED:
// wave w owns cone slot w for ALL 64 kout (4 independent q-subtiles -> ILP).
// af fragments built ONCE per link (kout-independent). 256 blocks x 512 thr;
// block c owns links 4c..4c+3 with 2-link truncated margins; fwd-cone skip.
// Gate pre-activations arrive pre-scaled (log2e / 2*log2e) -> native exp2.
// ---------------------------------------------------------------------------
__global__ __launch_bounds__(512, 1) void gru_cone(
    const _Float16* __restrict__ Wpk,
    const float* __restrict__ att,  const float* __restrict__ params,
    const float* __restrict__ w_fc, const float* __restrict__ b_fc,
    float* __restrict__ out)
{
    const int c    = chunk_of_block(blockIdx.x);
    const int tid  = threadIdx.x;
    const int w    = tid >> 6, lane = tid & 63;
    const int n    = lane & 15, kq = lane >> 4;
    const int cl   = w;               // cone slot 0..7 (this wave's link)
    const int base = 4 * c - MARG;

    __shared__ __align__(16) _Float16 hbuf[2 * CONE * 32 * 64];  // 64 KB
    __shared__ __align__(16) _Float16 xls[CONE][1536];           // 24 KB
    __shared__ float psum[4][B_];                                // 0.5 KB

    // ---- stage x for the 8 cone links (f32 -> f16), coalesced
    #pragma unroll
    for (int i = 0; i < 24; ++i) {
        const int e  = i * 512 + tid;        // 0..12287
        const int sl = e / 1536, rem = e % 1536;
        const int gs = clampi(base + sl, 0, L_ - 1);
        xls[sl][rem] = (_Float16)params[(size_t)gs * NROWS + rem];
    }
    // ---- zero both h parities (8192 u64)
    #pragma unroll
    for (int i = 0; i < 16; ++i)
        ((u64*)hbuf)[i * 512 + tid] = 0ull;

    // ---- this wave's task constants (one link, all 64 kout)
    const int  gl   = base + cl;
    const bool tval = (gl >= 0 && gl < L_);
    const int  glc  = clampi(gl, 0, L_ - 1);
    const _Float16 ach = tval ? (_Float16)att[(size_t)glc * L_ + glc] : (_Float16)0.0f;
    const _Float16 alh = (tval && cl > 0 && gl > 0)
                           ? (_Float16)att[(size_t)glc * L_ + glc - 1] : (_Float16)0.0f;
    const _Float16 arh = (tval && cl < CONE - 1 && gl < L_ - 1)
                           ? (_Float16)att[(size_t)glc * L_ + glc + 1] : (_Float16)0.0f;
    float bnh[4][4];   // per-q, per-r nh bias, pre-scaled by 2*log2e
    f16x8 xw[4][3];    // hoisted x-frags [q][gate] (bias row folded)
    {
        const float* pb = params + (size_t)glc * NROWS + 1536;
        #pragma unroll
        for (int q = 0; q < 4; ++q) {
            #pragma unroll
            for (int r = 0; r < 4; ++r)
                bnh[q][r] = pb[256 + q * 16 + kq * 4 + r] * LOG2E2;
            #pragma unroll
            for (int g = 0; g < 3; ++g)
                xw[q][g] = *(const f16x8*)(Wpk +
                    (((size_t)glc * 36 + q * 9 + 2 + 3 * g) * 64 + lane) * 8);
        }
    }
    __syncthreads();

    // ---- time loop: fully block-local
    #pragma unroll 1
    for (int t = 0; t < T_; ++t) {
        const int rp = t & 1, wpb = rp ^ 1;
        const int need = T_ - 1 - t;                  // forward-cone radius
        const char* hbr = (const char*)hbuf;
        char*       hbw = (char*)hbuf;

        if (tval && cl >= 2 - need && cl <= 5 + need) {
            const bool hid = (t > 0);

            // B-operand fragments (hatt) from LDS, built once for all 4 q
            f16x8 af[2][2];
            if (hid) {
                #pragma unroll
                for (int mt = 0; mt < 2; ++mt)
                    #pragma unroll
                    for (int ks = 0; ks < 2; ++ks) {
                        const int b = mt * 16 + n, k0 = ks * 32 + kq * 8;
                        const int sl = (cl > 0) ? cl - 1 : 0;
                        const int sr = (cl < CONE - 1) ? cl + 1 : CONE - 1;
                        const f16x8 hs = *(const f16x8*)(hbr + h_byte(rp, cl, b, k0));
                        const f16x8 hl = *(const f16x8*)(hbr + h_byte(rp, sl, b, k0));
                        const f16x8 hr = *(const f16x8*)(hbr + h_byte(rp, sr, b, k0));
                        af[mt][ks] = ach * hs + alh * hl + arh * hr;
                    }
            }
            // x B-fragment (K rows 0..3 = features, row 4 = 1.0 for bias)
            f16x8 ax[2] = {};
            if (kq == 0) {
                #pragma unroll
                for (int mt = 0; mt < 2; ++mt) {
                    #pragma unroll
                    for (int f = 0; f < 4; ++f)
                        ax[mt][f] = xls[cl][(mt * 16 + n) * 48 + t * 4 + f];
                    ax[mt][4] = (_Float16)1.0f;
                }
            }

            float sfc[2] = {0.0f, 0.0f};
            #pragma unroll
            for (int q = 0; q < 4; ++q) {
                const int kb = q * 16 + kq * 4;           // this thread's kout run
                const _Float16* wb = Wpk + (((size_t)gl * 36 + q * 9) * 64) * 8;
                f32x4 ar[2] = {}, az[2] = {}, anh_[2] = {}, anx_[2] = {};
                if (hid) {
                    const f16x8 b0 = *(const f16x8*)(wb + (0 * 64 + lane) * 8);
                    const f16x8 b1 = *(const f16x8*)(wb + (1 * 64 + lane) * 8);
                    const f16x8 b3 = *(const f16x8*)(wb + (3 * 64 + lane) * 8);
                    const f16x8 b4 = *(const f16x8*)(wb + (4 * 64 + lane) * 8);
                    const f16x8 b6 = *(const f16x8*)(wb + (6 * 64 + lane) * 8);
                    const f16x8 b7 = *(const f16x8*)(wb + (7 * 64 + lane) * 8);
                    #pragma unroll
                    for (int mt = 0; mt < 2; ++mt) {
                        ar[mt]   = MFMA(b0, af[mt][0], ar[mt],   0, 0, 0);
                        ar[mt]   = MFMA(b1, af[mt][1], ar[mt],   0, 0, 0);
                        az[mt]   = MFMA(b3, af[mt][0], az[mt],   0, 0, 0);
                        az[mt]   = MFMA(b4, af[mt][1], az[mt],   0, 0, 0);
                        anh_[mt] = MFMA(b6, af[mt][0], anh_[mt], 0, 0, 0);
                        anh_[mt] = MFMA(b7, af[mt][1], anh_[mt], 0, 0, 0);
                    }
                }
                #pragma unroll
                for (int mt = 0; mt < 2; ++mt) {
                    ar[mt]   = MFMA(xw[q][0], ax[mt], ar[mt],   0, 0, 0);
                    az[mt]   = MFMA(xw[q][1], ax[mt], az[mt],   0, 0, 0);
                    anx_[mt] = MFMA(xw[q][2], ax[mt], anx_[mt], 0, 0, 0);
                }
                float4 wfc4;
                if (t == T_ - 1)
                    wfc4 = *(const float4*)&w_fc[(size_t)gl * H_ + kb];
                #pragma unroll
                for (int mt = 0; mt < 2; ++mt) {
                    const int b = mt * 16 + n;
                    // z-blend previous state: one contiguous b64 (4 kout)
                    union { u64 u; _Float16 h[4]; } hp;
                    hp.u = hid ? *(const u64*)(hbr + h_byte(rp, cl, b, kb)) : 0ull;
                    union { u64 u; _Float16 h[4]; } hvp;
                    #pragma unroll
                    for (int r = 0; r < 4; ++r) {
                        // pre-scaled pre-activations -> native 2^x throughout
                        const float rg = __builtin_amdgcn_rcpf(1.0f + EXP2F(-ar[mt][r]));
                        const float zg = __builtin_amdgcn_rcpf(1.0f + EXP2F(-az[mt][r]));
                        float npre = anx_[mt][r] + rg * (anh_[mt][r] + bnh[q][r]);
                        npre = fminf(fmaxf(npre, -43.0f), 43.0f);
                        const float e2 = EXP2F(npre);
                        const float nn = (e2 - 1.0f) * __builtin_amdgcn_rcpf(e2 + 1.0f);
                        const float hv = (1.0f - zg) * nn + zg * (float)hp.h[r];
                        hvp.h[r] = (_Float16)hv;
                        if (t == T_ - 1) sfc[mt] += hv * (&wfc4.x)[r];
                    }
                    if (t < T_ - 1)
                        *(u64*)(hbw + h_byte(wpb, cl, b, kb)) = hvp.u;
                }
            }
            if (t == T_ - 1) {   // only own slots (cl 2..5) reach here
                #pragma unroll
                for (int mt = 0; mt < 2; ++mt) {
                    float s = sfc[mt];
                    s += __shfl_xor(s, 16, 64);   // reduce over kq
                    s += __shfl_xor(s, 32, 64);
                    if (kq == 0) psum[cl - 2][mt * 16 + n] = s;
                }
            }
        }
        __syncthreads();   // h[wpb] complete (and, at t=11, psum complete)
    }

    // ---- FC combine epilogue
    if (tid < 128) {
        const int o = tid >> 5, b = tid & 31;
        const int gl2 = 4 * c + o;
        out[(size_t)b * L_ + gl2] = psum[o][b] + b_fc[gl2];
    }
}

extern "C" void kernel_launch(void* const* d_in, const int* in_sizes, int n_in,
                              void* d_out, int out_size, void* d_ws, size_t ws_size,
                              hipStream_t stream) {
    const float* x    = (const float*)d_in[0];
    const float* att  = (const float*)d_in[1];
    const float* w_rh = (const float*)d_in[2];
    const float* b_rh = (const float*)d_in[3];
    const float* w_ri = (const float*)d_in[4];
    const float* b_ri = (const float*)d_in[5];
    const float* w_uh = (const float*)d_in[6];
    const float* b_uh = (const float*)d_in[7];
    const float* w_ui = (const float*)d_in[8];
    const float* b_ui = (const float*)d_in[9];
    const float* w_nh = (const float*)d_in[10];
    const float* b_nh = (const float*)d_in[11];
    const float* w_ni = (const float*)d_in[12];
    const float* b_ni = (const float*)d_in[13];
    const float* w_fc = (const float*)d_in[14];
    const float* b_fc = (const float*)d_in[15];
    float* out = (float*)d_out;

    char* ws = (char*)d_ws;
    float*    params = (float*)ws;                    // 7.9 MB
    _Float16* Wpk    = (_Float16*)(ws + (8u << 20));  // 37.7 MB packed weights

    prep_all<<<1504, 256, 0, stream>>>(x, b_rh, b_ri, b_uh, b_ui, b_nh, b_ni,
                                       w_rh, w_uh, w_nh, w_ri, w_ui, w_ni,
                                       params, Wpk);
    gru_cone<<<NCH, 512, 0, stream>>>(Wpk, att, params, w_fc, b_fc, out);
}